// Round 2
// baseline (394.446 us; speedup 1.0000x reference)
//
#include <hip/hip_runtime.h>
#include <hip/hip_cooperative_groups.h>

namespace cg = cooperative_groups;

#define B_   2
#define T_   5
#define N_   4096
#define C_   16
#define D_   128
#define S_   4
#define NS_  16384   // (T-1)*N
#define M_   8192    // B*N
#define EPS_ 1e-5f
#define NPART 32     // atomic partial buffers (contention killer)

// ---- ws layout (fp32 element offsets) ----
#define HX_OFF   0u         // hmax: M*128
#define HN_OFF   1048576u   // hmin: M*128
#define Y_OFF    2097152u   // y: 3*M*128
#define ST_OFF   5242880u   // stats partials: 32*256 (bn1) + 32*768 (branch) = 32768
#define WL_OFF   5275648u   // [0]=count (int), [1..8192]=straggler ids
#define ID4_OFF  5283848u   // int4 per query: (i0,i1,i2,cnt)
#define WP_OFF   5316616u   // packed transposed FC weights: 3*16384
#define PK_OFF   5365768u   // SoA scan data: 2*16384 float4
// bn1 partial p: st[p*256 + (0..127 sum | 128..255 sumsq)]
// branch partial p, branch k: st[8192 + p*768 + k*256 + (0..127 sum | 128..255 sq)]

#define OUT_FEAT 57344      // element offset of feature within d_out (fp32)

// ============================ phase bodies ============================
// All phases assume grid 512 x 256. They are shared between the fused
// cooperative kernel and the 5-kernel fallback path.

__device__ __forceinline__ void prep_phase(int bid, int tid,
    const float* __restrict__ x,
    const float* __restrict__ fw1, const float* __restrict__ fw2,
    const float* __restrict__ fw3,
    float* __restrict__ st, int* __restrict__ wcnt,
    float4* __restrict__ wp, float4* __restrict__ pk4)
{
    int gtid = bid * 256 + tid;                 // 0..131071
    if (gtid < 32768) {                         // pk4[b][j] = (px,py,pz,|p|^2)
        int b = gtid >> 14, j = gtid & 16383;
        const float* p = x + (size_t)b * (T_ * N_ * C_) + N_ * C_ + (size_t)j * 16;
        float4 v = *(const float4*)p;
        float pn = (v.x * v.x + v.y * v.y) + v.z * v.z;   // same expr as scan
        pk4[gtid] = make_float4(v.x, v.y, v.z, pn);
    }
    if (gtid < 4096) {                          // zero 32768 stats floats
        #pragma unroll
        for (int i = 0; i < 8; i++) st[gtid + 4096 * i] = 0.0f;
    }
    if (gtid == 0) wcnt[0] = 0;
    if (gtid < 12288) {                         // pack FC weights transposed
        int k = gtid >> 12, t0 = gtid & 4095;
        int o = t0 >> 5, c4 = t0 & 31;
        const float* fw = (k == 0) ? fw1 : ((k == 1) ? fw2 : fw3);
        wp[k * 4096 + c4 * 128 + o] = *(const float4*)(fw + o * 128 + c4 * 4);
    }
}

// Phase 1: 4 queries per wave, CHUNK 0 ONLY (512 pts, L2-hot).
// Complete (cnt==4): gather+conv1 -> hmax/hmin, stats in registers.
// Incomplete: enqueue. One LDS reduce + ONE atomic set per block.
// smem: 1024 floats (red[2][512]).
__device__ __forceinline__ void ball1_phase(int bid, int tid, float* smem,
    const float* __restrict__ x, const float* __restrict__ w,
    const float* __restrict__ bias, const float4* __restrict__ pk4,
    float* __restrict__ hx, float* __restrict__ hn, float* __restrict__ st,
    int* __restrict__ wcnt, int* __restrict__ wl, int4* __restrict__ id4)
{
    int wid = tid >> 6, lane = tid & 63;
    float* red0 = smem;
    float* red1 = smem + 512;

    float wc0[16], wc1[16];                     // conv1 rows lane, lane+64
    #pragma unroll
    for (int j = 0; j < 4; j++) {
        float4 a = *(const float4*)(w + lane * 16 + j * 4);
        float4 b2 = *(const float4*)(w + (lane + 64) * 16 + j * 4);
        wc0[j*4+0] = a.x;  wc0[j*4+1] = a.y;  wc0[j*4+2] = a.z;  wc0[j*4+3] = a.w;
        wc1[j*4+0] = b2.x; wc1[j*4+1] = b2.y; wc1[j*4+2] = b2.z; wc1[j*4+3] = b2.w;
    }
    float bo0 = bias[lane], bo1 = bias[lane + 64];

    float asum0 = 0.0f, asq0 = 0.0f, asum1 = 0.0f, asq1 = 0.0f;
    for (int qi = 0; qi < 4; qi++) {
        int m = (bid * 4 + wid) * 4 + qi;       // covers 0..8191
        int b = m >> 12, q = m & (N_ - 1);
        const float* xb = x + (size_t)b * (T_ * N_ * C_);
        const float* pts = xb + N_ * C_;
        const float4* pk = pk4 + b * 16384;
        float qx = xb[q * 16 + 0];
        float qy = xb[q * 16 + 1];
        float qz = xb[q * 16 + 2];
        float qn = (qx * qx + qy * qy) + qz * qz;

        float4 pv[8];
        #pragma unroll
        for (int u = 0; u < 8; u++) pv[u] = pk[u * 64 + lane];
        unsigned long long mk[8];
        #pragma unroll
        for (int u = 0; u < 8; u++) {
            float dot = (qx * pv[u].x + qy * pv[u].y) + qz * pv[u].z;
            mk[u] = __ballot((qn + pv[u].w) - 2.0f * dot < 1.0f);   // ref form
        }

        // extract first 4 set bits (ascending index) without scratch
        int i0 = 0, i1 = 0, i2 = 0, i3 = 0, cnt = 0;
        unsigned long long m0 = mk[0];
        if (__builtin_popcountll(m0) >= 4) {    // fast path: ~95% of queries
            i0 = __builtin_ctzll(m0); m0 &= m0 - 1;
            i1 = __builtin_ctzll(m0); m0 &= m0 - 1;
            i2 = __builtin_ctzll(m0); m0 &= m0 - 1;
            i3 = __builtin_ctzll(m0);
            cnt = 4;
        } else {
            #pragma unroll
            for (int u = 0; u < 8; u++) {
                unsigned long long mask = mk[u];
                while (mask && cnt < 4) {       // wave-uniform
                    int id = u * 64 + __builtin_ctzll(mask);
                    if (cnt == 0)      i0 = id;
                    else if (cnt == 1) i1 = id;
                    else if (cnt == 2) i2 = id;
                    else               i3 = id;
                    cnt++;
                    mask &= (mask - 1);
                }
            }
        }

        if (cnt >= 4) {                         // complete: conv + hmax/hmin
            int ids[4] = {i0, i1, i2, i3};      // static-indexed below
            float a0[4], a1[4];
            #pragma unroll
            for (int s = 0; s < 4; s++) {
                const float* rp = pts + (size_t)ids[s] * 16;
                float4 r0 = *(const float4*)(rp);
                float4 r1 = *(const float4*)(rp + 4);
                float4 r2 = *(const float4*)(rp + 8);
                float4 r3 = *(const float4*)(rp + 12);
                float s0 = bo0, s1 = bo1;
                s0 += wc0[0] * r0.x;  s0 += wc0[1] * r0.y;  s0 += wc0[2] * r0.z;  s0 += wc0[3] * r0.w;
                s0 += wc0[4] * r1.x;  s0 += wc0[5] * r1.y;  s0 += wc0[6] * r1.z;  s0 += wc0[7] * r1.w;
                s0 += wc0[8] * r2.x;  s0 += wc0[9] * r2.y;  s0 += wc0[10] * r2.z; s0 += wc0[11] * r2.w;
                s0 += wc0[12] * r3.x; s0 += wc0[13] * r3.y; s0 += wc0[14] * r3.z; s0 += wc0[15] * r3.w;
                s1 += wc1[0] * r0.x;  s1 += wc1[1] * r0.y;  s1 += wc1[2] * r0.z;  s1 += wc1[3] * r0.w;
                s1 += wc1[4] * r1.x;  s1 += wc1[5] * r1.y;  s1 += wc1[6] * r1.z;  s1 += wc1[7] * r1.w;
                s1 += wc1[8] * r2.x;  s1 += wc1[9] * r2.y;  s1 += wc1[10] * r2.z; s1 += wc1[11] * r2.w;
                s1 += wc1[12] * r3.x; s1 += wc1[13] * r3.y; s1 += wc1[14] * r3.z; s1 += wc1[15] * r3.w;
                a0[s] = s0; a1[s] = s1;
            }
            hx[(size_t)m * 128 + lane]      = fmaxf(fmaxf(a0[0], a0[1]), fmaxf(a0[2], a0[3]));
            hx[(size_t)m * 128 + 64 + lane] = fmaxf(fmaxf(a1[0], a1[1]), fmaxf(a1[2], a1[3]));
            hn[(size_t)m * 128 + lane]      = fminf(fminf(a0[0], a0[1]), fminf(a0[2], a0[3]));
            hn[(size_t)m * 128 + 64 + lane] = fminf(fminf(a1[0], a1[1]), fminf(a1[2], a1[3]));
            asum0 += (a0[0] + a0[1]) + (a0[2] + a0[3]);
            asq0  += (a0[0] * a0[0] + a0[1] * a0[1]) + (a0[2] * a0[2] + a0[3] * a0[3]);
            asum1 += (a1[0] + a1[1]) + (a1[2] + a1[3]);
            asq1  += (a1[0] * a1[0] + a1[1] * a1[1]) + (a1[2] * a1[2] + a1[3] * a1[3]);
        } else {                                // straggler: enqueue
            if (lane == 0) {
                int idx = atomicAdd(wcnt, 1);
                wl[idx] = m;
                id4[m] = make_int4(i0, i1, i2, cnt);
            }
        }
    }

    red0[wid * 128 + lane]      = asum0;
    red0[wid * 128 + 64 + lane] = asum1;
    red1[wid * 128 + lane]      = asq0;
    red1[wid * 128 + 64 + lane] = asq1;
    __syncthreads();
    if (tid < 128) {
        float* stp = st + (bid & (NPART - 1)) * 256;
        float s0 = (red0[tid] + red0[128 + tid]) + (red0[256 + tid] + red0[384 + tid]);
        float s1 = (red1[tid] + red1[128 + tid]) + (red1[256 + tid] + red1[384 + tid]);
        atomicAdd(&stp[tid], s0);
        atomicAdd(&stp[128 + tid], s1);
    }
}

// Phase 2: grid-stride the worklist. 4 waves scan 8 chunks each (2-deep
// pipelining), LDS merge first-4-by-index with phase-1 partial, wave 0:
// gather+conv+hmax/hmin. ONE atomic set per participating block at the end.
// smem: 32 floats (aliased as int sCnt[4], int sIds[4][4]).
__device__ __forceinline__ void ball2_phase(int bid, int tid, float* smem,
    const float* __restrict__ x, const float* __restrict__ w,
    const float* __restrict__ bias, const float4* __restrict__ pk4,
    float* __restrict__ hx, float* __restrict__ hn, float* __restrict__ st,
    const int* __restrict__ wcnt, const int* __restrict__ wl,
    const int4* __restrict__ id4)
{
    int wid = tid >> 6, lane = tid & 63;
    int* sCnt = (int*)smem;                     // 4 ints
    int* sIds = (int*)smem + 4;                 // 16 ints, [w][i] = sIds[w*4+i]

    float wc0[16], wc1[16];
    float bo0 = 0.0f, bo1 = 0.0f;
    if (wid == 0) {
        #pragma unroll
        for (int j = 0; j < 4; j++) {
            float4 a = *(const float4*)(w + lane * 16 + j * 4);
            float4 b2 = *(const float4*)(w + (lane + 64) * 16 + j * 4);
            wc0[j*4+0] = a.x;  wc0[j*4+1] = a.y;  wc0[j*4+2] = a.z;  wc0[j*4+3] = a.w;
            wc1[j*4+0] = b2.x; wc1[j*4+1] = b2.y; wc1[j*4+2] = b2.z; wc1[j*4+3] = b2.w;
        }
        bo0 = bias[lane]; bo1 = bias[lane + 64];
    }
    float asum0 = 0.0f, asq0 = 0.0f, asum1 = 0.0f, asq1 = 0.0f;

    int nstrag = *wcnt;
    for (int e = bid; e < nstrag; e += 512) {
        int m = wl[e];
        int b = m >> 12, q = m & (N_ - 1);
        const float* xb = x + (size_t)b * (T_ * N_ * C_);
        const float* pts = xb + N_ * C_;
        const float4* pk = pk4 + b * 16384;
        float qx = xb[q * 16 + 0];
        float qy = xb[q * 16 + 1];
        float qz = xb[q * 16 + 2];
        float qn = (qx * qx + qy * qy) + qz * qz;

        int cstart = 1 + 8 * wid;
        int cend = cstart + 8; if (cend > 32) cend = 32;
        int y0 = 0, y1 = 0, y2 = 0, y3 = 0;     // named, no scratch
        int myc = 0;
        for (int c = cstart; c < cend && myc < 4; c += 2) {
            bool two = (c + 1 < cend);
            float4 pva[8], pvb[8];
            #pragma unroll
            for (int u = 0; u < 8; u++) pva[u] = pk[c * 512 + u * 64 + lane];
            if (two) {
                #pragma unroll
                for (int u = 0; u < 8; u++) pvb[u] = pk[(c + 1) * 512 + u * 64 + lane];
            }
            unsigned long long ma[8], mb[8];
            #pragma unroll
            for (int u = 0; u < 8; u++) {
                float dot = (qx * pva[u].x + qy * pva[u].y) + qz * pva[u].z;
                ma[u] = __ballot((qn + pva[u].w) - 2.0f * dot < 1.0f);
            }
            if (two) {
                #pragma unroll
                for (int u = 0; u < 8; u++) {
                    float dot = (qx * pvb[u].x + qy * pvb[u].y) + qz * pvb[u].z;
                    mb[u] = __ballot((qn + pvb[u].w) - 2.0f * dot < 1.0f);
                }
            }
            #pragma unroll
            for (int u = 0; u < 8; u++) {
                unsigned long long mask = ma[u];
                while (mask && myc < 4) {
                    int id = c * 512 + u * 64 + __builtin_ctzll(mask);
                    if (myc == 0)      y0 = id;
                    else if (myc == 1) y1 = id;
                    else if (myc == 2) y2 = id;
                    else               y3 = id;
                    myc++;
                    mask &= (mask - 1);
                }
            }
            if (two) {
                #pragma unroll
                for (int u = 0; u < 8; u++) {
                    unsigned long long mask = mb[u];
                    while (mask && myc < 4) {
                        int id = (c + 1) * 512 + u * 64 + __builtin_ctzll(mask);
                        if (myc == 0)      y0 = id;
                        else if (myc == 1) y1 = id;
                        else if (myc == 2) y2 = id;
                        else               y3 = id;
                        myc++;
                        mask &= (mask - 1);
                    }
                }
            }
        }
        if (lane == 0) {
            sCnt[wid] = myc;
            sIds[wid * 4 + 0] = y0; sIds[wid * 4 + 1] = y1;
            sIds[wid * 4 + 2] = y2; sIds[wid * 4 + 3] = y3;
        }
        __syncthreads();

        if (wid == 0) {                         // merge + epilogue on wave 0
            int4 p1 = id4[m];
            int f0 = 0, f1 = 0, f2 = 0, f3 = 0; // named, no scratch
            int fc = p1.w;
            if (fc > 0) f0 = p1.x;
            if (fc > 1) f1 = p1.y;
            if (fc > 2) f2 = p1.z;
            #pragma unroll
            for (int w2 = 0; w2 < 4; w2++) {
                int c2 = sCnt[w2];
                #pragma unroll
                for (int i = 0; i < 4; i++) {
                    if (i < c2 && fc < 4) {
                        int id = sIds[w2 * 4 + i];
                        if (fc == 0)      f0 = id;
                        else if (fc == 1) f1 = id;
                        else if (fc == 2) f2 = id;
                        else              f3 = id;
                        fc++;
                    }
                }
            }
            if (fc >= 1) {
                if (fc <= 1) f1 = f0;
                if (fc <= 2) f2 = f0;
                if (fc <= 3) f3 = f0;
            }
            int fin[4] = {f0, f1, f2, f3};      // static-indexed below
            float a0[4], a1[4];
            if (fc == 0) {
                #pragma unroll
                for (int s = 0; s < 4; s++) { a0[s] = bo0; a1[s] = bo1; }
            } else {
                #pragma unroll
                for (int s = 0; s < 4; s++) {
                    const float* rp = pts + (size_t)fin[s] * 16;
                    float4 r0 = *(const float4*)(rp);
                    float4 r1 = *(const float4*)(rp + 4);
                    float4 r2 = *(const float4*)(rp + 8);
                    float4 r3 = *(const float4*)(rp + 12);
                    float s0 = bo0, s1 = bo1;
                    s0 += wc0[0] * r0.x;  s0 += wc0[1] * r0.y;  s0 += wc0[2] * r0.z;  s0 += wc0[3] * r0.w;
                    s0 += wc0[4] * r1.x;  s0 += wc0[5] * r1.y;  s0 += wc0[6] * r1.z;  s0 += wc0[7] * r1.w;
                    s0 += wc0[8] * r2.x;  s0 += wc0[9] * r2.y;  s0 += wc0[10] * r2.z; s0 += wc0[11] * r2.w;
                    s0 += wc0[12] * r3.x; s0 += wc0[13] * r3.y; s0 += wc0[14] * r3.z; s0 += wc0[15] * r3.w;
                    s1 += wc1[0] * r0.x;  s1 += wc1[1] * r0.y;  s1 += wc1[2] * r0.z;  s1 += wc1[3] * r0.w;
                    s1 += wc1[4] * r1.x;  s1 += wc1[5] * r1.y;  s1 += wc1[6] * r1.z;  s1 += wc1[7] * r1.w;
                    s1 += wc1[8] * r2.x;  s1 += wc1[9] * r2.y;  s1 += wc1[10] * r2.z; s1 += wc1[11] * r2.w;
                    s1 += wc1[12] * r3.x; s1 += wc1[13] * r3.y; s1 += wc1[14] * r3.z; s1 += wc1[15] * r3.w;
                    a0[s] = s0; a1[s] = s1;
                }
            }
            hx[(size_t)m * 128 + lane]      = fmaxf(fmaxf(a0[0], a0[1]), fmaxf(a0[2], a0[3]));
            hx[(size_t)m * 128 + 64 + lane] = fmaxf(fmaxf(a1[0], a1[1]), fmaxf(a1[2], a1[3]));
            hn[(size_t)m * 128 + lane]      = fminf(fminf(a0[0], a0[1]), fminf(a0[2], a0[3]));
            hn[(size_t)m * 128 + 64 + lane] = fminf(fminf(a1[0], a1[1]), fminf(a1[2], a1[3]));
            asum0 += (a0[0] + a0[1]) + (a0[2] + a0[3]);
            asq0  += (a0[0] * a0[0] + a0[1] * a0[1]) + (a0[2] * a0[2] + a0[3] * a0[3]);
            asum1 += (a1[0] + a1[1]) + (a1[2] + a1[3]);
            asq1  += (a1[0] * a1[0] + a1[1] * a1[1]) + (a1[2] * a1[2] + a1[3] * a1[3]);
        }
        __syncthreads();                        // LDS safe for next entry
    }
    if (wid == 0 && bid < nstrag) {             // only blocks that did work
        float* stp = st + (bid & (NPART - 1)) * 256;
        atomicAdd(&stp[lane], asum0);
        atomicAdd(&stp[64 + lane], asum1);
        atomicAdd(&stp[128 + lane], asq0);
        atomicAdd(&stp[192 + lane], asq1);
    }
}

// Phase 3: m-tile 16. bn1 finalize from 32 partials; r = max(sc*hmax,
// sc*hmin)+sh; feature out; 3x 128x128 FC; y write + branch stats.
// smem: 2304 floats (hs[2048] + scsh[256]).
__device__ __forceinline__ void fc_phase(int bid, int tid, float* smem,
    const float* __restrict__ hx, const float* __restrict__ hn,
    float* __restrict__ st, const float4* __restrict__ wp,
    const float* __restrict__ b1, const float* __restrict__ b2,
    const float* __restrict__ b3, const float* __restrict__ bng,
    const float* __restrict__ bnb, float* __restrict__ y,
    float* __restrict__ out)
{
    int m0 = bid * 16;
    float* hs = smem;                           // 2048
    float* scsh = smem + 2048;                  // 256

    if (tid < 128) {                            // bn1 finalize from partials
        float s = 0.0f, q2 = 0.0f;
        #pragma unroll
        for (int p = 0; p < NPART; p++) {
            s  += st[p * 256 + tid];
            q2 += st[p * 256 + 128 + tid];
        }
        float mean = s * (1.0f / 32768.0f);
        float var = q2 * (1.0f / 32768.0f) - mean * mean;
        float sc = bng[tid] / sqrtf(fmaxf(var, 0.0f) + EPS_);
        scsh[tid] = sc;
        scsh[128 + tid] = bnb[tid] - mean * sc;
    }
    __syncthreads();

    for (int i = tid; i < 16 * 128; i += 256) {
        int ml = i >> 7, o = i & 127;
        float vx = hx[(size_t)(m0 + ml) * 128 + o];
        float vn = hn[(size_t)(m0 + ml) * 128 + o];
        float sc = scsh[o];
        float r = fmaxf(sc * vx, sc * vn) + scsh[128 + o];
        hs[ml * 128 + o] = r;
        out[(size_t)OUT_FEAT + (size_t)(m0 + ml) * 128 + o] = r;
    }
    __syncthreads();

    int o = tid & 127, gr = tid >> 7;
    int mbase = gr * 8;
    float acc[3][8];
    {
        float bb0 = b1[o], bb1 = b2[o], bb2 = b3[o];
        #pragma unroll
        for (int mm = 0; mm < 8; mm++) {
            acc[0][mm] = bb0; acc[1][mm] = bb1; acc[2][mm] = bb2;
        }
    }
    for (int c4 = 0; c4 < 32; c4++) {
        float4 w1v = wp[c4 * 128 + o];
        float4 w2v = wp[4096 + c4 * 128 + o];
        float4 w3v = wp[8192 + c4 * 128 + o];
        const float* hp = &hs[mbase * 128 + c4 * 4];
        #pragma unroll
        for (int mm = 0; mm < 8; mm++) {
            float4 hv = *(const float4*)(hp + mm * 128);
            acc[0][mm] += w1v.x * hv.x; acc[0][mm] += w1v.y * hv.y;
            acc[0][mm] += w1v.z * hv.z; acc[0][mm] += w1v.w * hv.w;
            acc[1][mm] += w2v.x * hv.x; acc[1][mm] += w2v.y * hv.y;
            acc[1][mm] += w2v.z * hv.z; acc[1][mm] += w2v.w * hv.w;
            acc[2][mm] += w3v.x * hv.x; acc[2][mm] += w3v.y * hv.y;
            acc[2][mm] += w3v.z * hv.z; acc[2][mm] += w3v.w * hv.w;
        }
    }
    __syncthreads();
    float psum[3], psq[3];
    #pragma unroll
    for (int k = 0; k < 3; k++) {
        float s = 0.0f, sq = 0.0f;
        float* yk = y + (size_t)k * M_ * 128;
        #pragma unroll
        for (int mm = 0; mm < 8; mm++) {
            float v = acc[k][mm];
            yk[(size_t)(m0 + mbase + mm) * 128 + o] = v;
            s += v; sq += v * v;
        }
        psum[k] = s; psq[k] = sq;
    }
    #pragma unroll
    for (int k = 0; k < 3; k++) {
        hs[(k * 2 + gr) * 128 + o] = psum[k];
        hs[768 + (k * 2 + gr) * 128 + o] = psq[k];
    }
    __syncthreads();
    float* bp = st + 8192 + (bid & (NPART - 1)) * 768;
    for (int t = tid; t < 384; t += 256) {
        int k = t >> 7, oo = t & 127;
        float s  = hs[(k * 2) * 128 + oo] + hs[(k * 2 + 1) * 128 + oo];
        float sq = hs[768 + (k * 2) * 128 + oo] + hs[768 + (k * 2 + 1) * 128 + oo];
        atomicAdd(&bp[k * 256 + oo], s);
        atomicAdd(&bp[k * 256 + 128 + oo], sq);
    }
}

// Phase 4: branch-BN finalize from 32 partials, bn+relu, head matmuls,
// 7 fp32 outputs per row. smem: 768 floats (bsc).
__device__ __forceinline__ void heads_phase(int bid, int tid, float* smem,
    const float* __restrict__ y, const float* __restrict__ st,
    const float* __restrict__ wce, const float* __restrict__ bce,
    const float* __restrict__ wlwh, const float* __restrict__ blwh,
    const float* __restrict__ wth, const float* __restrict__ bth,
    const float* __restrict__ bng, const float* __restrict__ bnb,
    float* __restrict__ out)
{
    float* bsc = smem;                          // 768
    for (int t = tid; t < 384; t += 256) {
        int k = t >> 7, o = t & 127;
        float s = 0.0f, q2 = 0.0f;
        #pragma unroll
        for (int p = 0; p < NPART; p++) {
            const float* bp = st + 8192 + p * 768 + k * 256;
            s  += bp[o];
            q2 += bp[128 + o];
        }
        float mean = s * (1.0f / 8192.0f);
        float var = q2 * (1.0f / 8192.0f) - mean * mean;
        float sc = bng[o] / sqrtf(fmaxf(var, 0.0f) + EPS_);
        bsc[k * 256 + o] = sc;
        bsc[k * 256 + 128 + o] = bnb[o] - mean * sc;
    }
    __syncthreads();

    int wave = tid >> 6, lane = tid & 63;
    const float* y1 = y;
    const float* y2 = y + (size_t)M_ * D_;
    const float* y3 = y + 2 * (size_t)M_ * D_;
    #pragma unroll
    for (int i = 0; i < 4; i++) {
        int m = bid * 16 + wave * 4 + i;
        float p[7] = {0, 0, 0, 0, 0, 0, 0};
        #pragma unroll
        for (int cc = 0; cc < 2; cc++) {
            int c = lane + 64 * cc;
            float v1 = fmaxf(y1[(size_t)m * D_ + c] * bsc[c] + bsc[128 + c], 0.0f);
            float v2 = fmaxf(y2[(size_t)m * D_ + c] * bsc[256 + c] + bsc[384 + c], 0.0f);
            float v3 = fmaxf(y3[(size_t)m * D_ + c] * bsc[512 + c] + bsc[640 + c], 0.0f);
            p[0] += v1 * wce[c];
            p[1] += v1 * wce[128 + c];
            p[2] += v1 * wce[256 + c];
            p[3] += v2 * wlwh[c];
            p[4] += v2 * wlwh[128 + c];
            p[5] += v2 * wlwh[256 + c];
            p[6] += v3 * wth[c];
        }
        #pragma unroll
        for (int off = 32; off > 0; off >>= 1) {
            #pragma unroll
            for (int j = 0; j < 7; j++) p[j] += __shfl_xor(p[j], off);
        }
        if (lane == 0) {
            out[m * 7 + 0] = p[0] + bce[0];
            out[m * 7 + 1] = p[1] + bce[1];
            out[m * 7 + 2] = p[2] + bce[2];
            out[m * 7 + 3] = p[3] + blwh[0];
            out[m * 7 + 4] = p[4] + blwh[1];
            out[m * 7 + 5] = p[5] + blwh[2];
            out[m * 7 + 6] = p[6] + bth[0];
        }
    }
}

// ============================ fused cooperative ============================
// 512 WGs x 256 = 8 waves/CU on 256 CUs — trivially co-resident.
__global__ __launch_bounds__(256, 2) void k_fused(
    const float* x, const float* conv1_w, const float* conv1_b,
    const float* fw1, const float* fw2, const float* fw3,
    const float* b1, const float* b2, const float* b3,
    const float* bng, const float* bnb,
    const float* wce, const float* bce,
    const float* wlwh, const float* blwh,
    const float* wth, const float* bth,
    float* hx, float* hn, float* y, float* st,
    int* wcnt, int* wl, int4* id4, float4* wp, float4* pk4,
    float* out)
{
    __shared__ float smem[2304];
    int bid = blockIdx.x, tid = threadIdx.x;
    cg::grid_group grid = cg::this_grid();

    prep_phase(bid, tid, x, fw1, fw2, fw3, st, wcnt, wp, pk4);
    grid.sync();
    ball1_phase(bid, tid, smem, x, conv1_w, conv1_b, pk4, hx, hn, st, wcnt, wl, id4);
    grid.sync();
    ball2_phase(bid, tid, smem, x, conv1_w, conv1_b, pk4, hx, hn, st, wcnt, wl, id4);
    grid.sync();
    fc_phase(bid, tid, smem, hx, hn, st, wp, b1, b2, b3, bng, bnb, y, out);
    grid.sync();
    heads_phase(bid, tid, smem, y, st, wce, bce, wlwh, blwh, wth, bth, bng, bnb, out);
}

// ============================ fallback wrappers ============================
__global__ __launch_bounds__(256) void k_prep(const float* __restrict__ x,
    const float* __restrict__ fw1, const float* __restrict__ fw2,
    const float* __restrict__ fw3, float* __restrict__ st,
    int* __restrict__ wcnt, float4* __restrict__ wp, float4* __restrict__ pk4) {
    prep_phase(blockIdx.x, threadIdx.x, x, fw1, fw2, fw3, st, wcnt, wp, pk4);
}
__global__ __launch_bounds__(256) void k_ball1(const float* __restrict__ x,
    const float* __restrict__ w, const float* __restrict__ bias,
    const float4* __restrict__ pk4, float* __restrict__ hx, float* __restrict__ hn,
    float* __restrict__ st, int* __restrict__ wcnt, int* __restrict__ wl,
    int4* __restrict__ id4) {
    __shared__ float smem[1024];
    ball1_phase(blockIdx.x, threadIdx.x, smem, x, w, bias, pk4, hx, hn, st, wcnt, wl, id4);
}
__global__ __launch_bounds__(256) void k_ball2(const float* __restrict__ x,
    const float* __restrict__ w, const float* __restrict__ bias,
    const float4* __restrict__ pk4, float* __restrict__ hx, float* __restrict__ hn,
    float* __restrict__ st, const int* __restrict__ wcnt, const int* __restrict__ wl,
    const int4* __restrict__ id4) {
    __shared__ float smem[32];
    ball2_phase(blockIdx.x, threadIdx.x, smem, x, w, bias, pk4, hx, hn, st, wcnt, wl, id4);
}
__global__ __launch_bounds__(256) void k_fc(const float* __restrict__ hx,
    const float* __restrict__ hn, float* __restrict__ st, const float4* __restrict__ wp,
    const float* __restrict__ b1, const float* __restrict__ b2,
    const float* __restrict__ b3, const float* __restrict__ bng,
    const float* __restrict__ bnb, float* __restrict__ y, float* __restrict__ out) {
    __shared__ float smem[2304];
    fc_phase(blockIdx.x, threadIdx.x, smem, hx, hn, st, wp, b1, b2, b3, bng, bnb, y, out);
}
__global__ __launch_bounds__(256) void k_heads(const float* __restrict__ y,
    const float* __restrict__ st, const float* __restrict__ wce,
    const float* __restrict__ bce, const float* __restrict__ wlwh,
    const float* __restrict__ blwh, const float* __restrict__ wth,
    const float* __restrict__ bth, const float* __restrict__ bng,
    const float* __restrict__ bnb, float* __restrict__ out) {
    __shared__ float smem[768];
    heads_phase(blockIdx.x, threadIdx.x, smem, y, st, wce, bce, wlwh, blwh, wth, bth, bng, bnb, out);
}

extern "C" void kernel_launch(void* const* d_in, const int* in_sizes, int n_in,
                              void* d_out, int out_size, void* d_ws, size_t ws_size,
                              hipStream_t stream) {
    (void)in_sizes; (void)n_in; (void)out_size; (void)ws_size;
    const float* x        = (const float*)d_in[0];
    const float* conv1_w  = (const float*)d_in[1];
    const float* conv1_b  = (const float*)d_in[2];
    const float* bn_g     = (const float*)d_in[3];
    const float* bn_b     = (const float*)d_in[4];
    const float* fc1_w    = (const float*)d_in[5];
    const float* fc1_b    = (const float*)d_in[6];
    const float* fc_ce_w  = (const float*)d_in[7];
    const float* fc_ce_b  = (const float*)d_in[8];
    const float* fc2_w    = (const float*)d_in[9];
    const float* fc2_b    = (const float*)d_in[10];
    const float* fc_lwh_w = (const float*)d_in[11];
    const float* fc_lwh_b = (const float*)d_in[12];
    const float* fc3_w    = (const float*)d_in[13];
    const float* fc3_b    = (const float*)d_in[14];
    const float* fc_th_w  = (const float*)d_in[15];
    const float* fc_th_b  = (const float*)d_in[16];

    float* ws = (float*)d_ws;
    float* hx = ws + HX_OFF;
    float* hn = ws + HN_OFF;
    float* y  = ws + Y_OFF;
    float* st = ws + ST_OFF;
    int*  wcnt = (int*)(ws + WL_OFF);
    int*  wl   = wcnt + 1;
    int4* id4  = (int4*)(ws + ID4_OFF);
    float4* wp  = (float4*)(ws + WP_OFF);
    float4* pk4 = (float4*)(ws + PK_OFF);
    float* out = (float*)d_out;

    void* args[] = {
        (void*)&x, (void*)&conv1_w, (void*)&conv1_b,
        (void*)&fc1_w, (void*)&fc2_w, (void*)&fc3_w,
        (void*)&fc1_b, (void*)&fc2_b, (void*)&fc3_b,
        (void*)&bn_g, (void*)&bn_b,
        (void*)&fc_ce_w, (void*)&fc_ce_b,
        (void*)&fc_lwh_w, (void*)&fc_lwh_b,
        (void*)&fc_th_w, (void*)&fc_th_b,
        (void*)&hx, (void*)&hn, (void*)&y, (void*)&st,
        (void*)&wcnt, (void*)&wl, (void*)&id4, (void*)&wp, (void*)&pk4,
        (void*)&out
    };
    hipError_t err = hipLaunchCooperativeKernel((const void*)k_fused,
                                                dim3(512), dim3(256),
                                                args, 0, stream);
    if (err != hipSuccess) {                    // fallback: 5-kernel path
        (void)hipGetLastError();                // clear sticky error
        hipLaunchKernelGGL(k_prep,  dim3(512), dim3(256), 0, stream,
                           x, fc1_w, fc2_w, fc3_w, st, wcnt, wp, pk4);
        hipLaunchKernelGGL(k_ball1, dim3(512), dim3(256), 0, stream,
                           x, conv1_w, conv1_b, pk4, hx, hn, st, wcnt, wl, id4);
        hipLaunchKernelGGL(k_ball2, dim3(512), dim3(256), 0, stream,
                           x, conv1_w, conv1_b, pk4, hx, hn, st, wcnt, wl, id4);
        hipLaunchKernelGGL(k_fc,    dim3(512), dim3(256), 0, stream, hx, hn, st, wp,
                           fc1_b, fc2_b, fc3_b, bn_g, bn_b, y, out);
        hipLaunchKernelGGL(k_heads, dim3(512), dim3(256), 0, stream, y, st,
                           fc_ce_w, fc_ce_b, fc_lwh_w, fc_lwh_b, fc_th_w, fc_th_b,
                           bn_g, bn_b, out);
    }
}

// Round 3
// 152.203 us; speedup vs baseline: 2.5916x; 2.5916x over previous
//
#include <hip/hip_runtime.h>

#define B_   2
#define T_   5
#define N_   4096
#define C_   16
#define D_   128
#define S_   4
#define NS_  16384   // (T-1)*N
#define M_   8192    // B*N
#define EPS_ 1e-5f
#define NPART 32     // atomic partial buffers (contention killer)

// ---- ws layout (fp32 element offsets) ----
#define HX_OFF   0u         // hmax: M*128
#define HN_OFF   1048576u   // hmin: M*128
#define Y_OFF    2097152u   // y: 3*M*128
#define ST_OFF   5242880u   // stats partials: 32*256 (bn1) + 32*768 (branch) = 32768
#define WL_OFF   5275648u   // [0]=count (int), [1..8192]=straggler ids
#define ID4_OFF  5283848u   // int4 per query: (i0,i1,i2,cnt)
#define WP_OFF   5316616u   // packed transposed FC weights: 3*16384
#define PK_OFF   5365768u   // SoA scan data: 2*16384 float4
// bn1 partial p: st[p*256 + (0..127 sum | 128..255 sumsq)]
// branch partial p, branch k: st[8192 + p*768 + k*256 + (0..127 sum | 128..255 sq)]

#define OUT_FEAT 57344      // element offset of feature within d_out (fp32)

// Phase 1 + prep: 1024 WGs x 256. Embedded prep (pk4 rows + wp packing) at
// the top — consumed only by LATER kernels (stream order guarantees
// visibility). Ball query on CHUNK 0 ONLY, computed directly from x (same
// expression as pk4, so ball2's values are bit-identical). Chunk-0 point
// data hoisted out of the query loop: loaded ONCE per wave (b is
// wave-uniform). 2 queries per wave. st zeroing done by host-side
// hipMemsetAsync before this kernel.
__global__ __launch_bounds__(256) void k_ball1(const float* __restrict__ x,
                                               const float* __restrict__ w,
                                               const float* __restrict__ bias,
                                               const float* __restrict__ fw1,
                                               const float* __restrict__ fw2,
                                               const float* __restrict__ fw3,
                                               float4* __restrict__ wp,
                                               float4* __restrict__ pk4,
                                               float* __restrict__ hx,
                                               float* __restrict__ hn,
                                               float* __restrict__ st,
                                               int* __restrict__ wcnt,
                                               int* __restrict__ wl,
                                               int4* __restrict__ id4) {
    int tid = threadIdx.x;
    int bid = blockIdx.x;
    int wid = tid >> 6, lane = tid & 63;
    __shared__ float red[2][512];

    // ---- embedded prep: pk4 (32 rows/block) ----
    if (tid < 32) {
        int row = bid * 32 + tid;               // 0..32767
        int b = row >> 14, j = row & 16383;
        const float* p = x + (size_t)b * (T_ * N_ * C_) + N_ * C_ + (size_t)j * 16;
        float4 v = *(const float4*)p;
        float pn = (v.x * v.x + v.y * v.y) + v.z * v.z;   // canonical expr
        pk4[row] = make_float4(v.x, v.y, v.z, pn);
    } else if (tid < 44) {                      // wp packing (12/block)
        int i = bid * 12 + (tid - 32);          // 0..12287
        int k = i >> 12, t0 = i & 4095;
        int o = t0 >> 5, c4 = t0 & 31;
        const float* fw = (k == 0) ? fw1 : ((k == 1) ? fw2 : fw3);
        wp[k * 4096 + c4 * 128 + o] = *(const float4*)(fw + o * 128 + c4 * 4);
    }

    // ---- conv1 weights: rows lane, lane+64 ----
    float wc0[16], wc1[16];
    #pragma unroll
    for (int j = 0; j < 4; j++) {
        float4 a = *(const float4*)(w + lane * 16 + j * 4);
        float4 b2 = *(const float4*)(w + (lane + 64) * 16 + j * 4);
        wc0[j*4+0] = a.x;  wc0[j*4+1] = a.y;  wc0[j*4+2] = a.z;  wc0[j*4+3] = a.w;
        wc1[j*4+0] = b2.x; wc1[j*4+1] = b2.y; wc1[j*4+2] = b2.z; wc1[j*4+3] = b2.w;
    }
    float bo0 = bias[lane], bo1 = bias[lane + 64];

    // ---- chunk-0 point data, loaded ONCE per wave (b wave-uniform) ----
    int mbase = (bid * 4 + wid) * 2;            // covers 0..8191, pairs never straddle batch
    int b = mbase >> 12;
    const float* xb = x + (size_t)b * (T_ * N_ * C_);
    const float* pts = xb + N_ * C_;
    float4 pv[8];
    #pragma unroll
    for (int u = 0; u < 8; u++) {
        const float* p = pts + (size_t)(u * 64 + lane) * 16;
        float4 v = *(const float4*)p;
        float pn = (v.x * v.x + v.y * v.y) + v.z * v.z;   // same bits as pk4
        pv[u] = make_float4(v.x, v.y, v.z, pn);
    }

    float asum0 = 0.0f, asq0 = 0.0f, asum1 = 0.0f, asq1 = 0.0f;
    #pragma unroll
    for (int qi = 0; qi < 2; qi++) {
        int m = mbase + qi;
        int q = m & (N_ - 1);
        float qx = xb[q * 16 + 0];
        float qy = xb[q * 16 + 1];
        float qz = xb[q * 16 + 2];
        float qn = (qx * qx + qy * qy) + qz * qz;

        unsigned long long mk[8];
        #pragma unroll
        for (int u = 0; u < 8; u++) {
            float dot = (qx * pv[u].x + qy * pv[u].y) + qz * pv[u].z;
            mk[u] = __ballot((qn + pv[u].w) - 2.0f * dot < 1.0f);   // ref form
        }

        // extract first 4 set bits (ascending index) without scratch
        int i0 = 0, i1 = 0, i2 = 0, i3 = 0, cnt = 0;
        unsigned long long m0 = mk[0];
        if (__builtin_popcountll(m0) >= 4) {    // fast path: ~95% of queries
            i0 = __builtin_ctzll(m0); m0 &= m0 - 1;
            i1 = __builtin_ctzll(m0); m0 &= m0 - 1;
            i2 = __builtin_ctzll(m0); m0 &= m0 - 1;
            i3 = __builtin_ctzll(m0);
            cnt = 4;
        } else {
            #pragma unroll
            for (int u = 0; u < 8; u++) {
                unsigned long long mask = mk[u];
                while (mask && cnt < 4) {       // wave-uniform
                    int id = u * 64 + __builtin_ctzll(mask);
                    if (cnt == 0)      i0 = id;
                    else if (cnt == 1) i1 = id;
                    else if (cnt == 2) i2 = id;
                    else               i3 = id;
                    cnt++;
                    mask &= (mask - 1);
                }
            }
        }

        if (cnt >= 4) {                         // complete: conv + hmax/hmin
            int ids[4] = {i0, i1, i2, i3};      // static-indexed below
            float a0[4], a1[4];
            #pragma unroll
            for (int s = 0; s < 4; s++) {
                const float* rp = pts + (size_t)ids[s] * 16;
                float4 r0 = *(const float4*)(rp);
                float4 r1 = *(const float4*)(rp + 4);
                float4 r2 = *(const float4*)(rp + 8);
                float4 r3 = *(const float4*)(rp + 12);
                float s0 = bo0, s1 = bo1;
                s0 += wc0[0] * r0.x;  s0 += wc0[1] * r0.y;  s0 += wc0[2] * r0.z;  s0 += wc0[3] * r0.w;
                s0 += wc0[4] * r1.x;  s0 += wc0[5] * r1.y;  s0 += wc0[6] * r1.z;  s0 += wc0[7] * r1.w;
                s0 += wc0[8] * r2.x;  s0 += wc0[9] * r2.y;  s0 += wc0[10] * r2.z; s0 += wc0[11] * r2.w;
                s0 += wc0[12] * r3.x; s0 += wc0[13] * r3.y; s0 += wc0[14] * r3.z; s0 += wc0[15] * r3.w;
                s1 += wc1[0] * r0.x;  s1 += wc1[1] * r0.y;  s1 += wc1[2] * r0.z;  s1 += wc1[3] * r0.w;
                s1 += wc1[4] * r1.x;  s1 += wc1[5] * r1.y;  s1 += wc1[6] * r1.z;  s1 += wc1[7] * r1.w;
                s1 += wc1[8] * r2.x;  s1 += wc1[9] * r2.y;  s1 += wc1[10] * r2.z; s1 += wc1[11] * r2.w;
                s1 += wc1[12] * r3.x; s1 += wc1[13] * r3.y; s1 += wc1[14] * r3.z; s1 += wc1[15] * r3.w;
                a0[s] = s0; a1[s] = s1;
            }
            hx[(size_t)m * 128 + lane]      = fmaxf(fmaxf(a0[0], a0[1]), fmaxf(a0[2], a0[3]));
            hx[(size_t)m * 128 + 64 + lane] = fmaxf(fmaxf(a1[0], a1[1]), fmaxf(a1[2], a1[3]));
            hn[(size_t)m * 128 + lane]      = fminf(fminf(a0[0], a0[1]), fminf(a0[2], a0[3]));
            hn[(size_t)m * 128 + 64 + lane] = fminf(fminf(a1[0], a1[1]), fminf(a1[2], a1[3]));
            asum0 += (a0[0] + a0[1]) + (a0[2] + a0[3]);
            asq0  += (a0[0] * a0[0] + a0[1] * a0[1]) + (a0[2] * a0[2] + a0[3] * a0[3]);
            asum1 += (a1[0] + a1[1]) + (a1[2] + a1[3]);
            asq1  += (a1[0] * a1[0] + a1[1] * a1[1]) + (a1[2] * a1[2] + a1[3] * a1[3]);
        } else {                                // straggler: enqueue
            if (lane == 0) {
                int idx = atomicAdd(wcnt, 1);
                wl[idx] = m;
                id4[m] = make_int4(i0, i1, i2, cnt);
            }
        }
    }

    red[0][wid * 128 + lane]      = asum0;
    red[0][wid * 128 + 64 + lane] = asum1;
    red[1][wid * 128 + lane]      = asq0;
    red[1][wid * 128 + 64 + lane] = asq1;
    __syncthreads();
    if (tid < 128) {
        float* stp = st + (bid & (NPART - 1)) * 256;
        float s0 = (red[0][tid] + red[0][128 + tid]) + (red[0][256 + tid] + red[0][384 + tid]);
        float s1 = (red[1][tid] + red[1][128 + tid]) + (red[1][256 + tid] + red[1][384 + tid]);
        atomicAdd(&stp[tid], s0);
        atomicAdd(&stp[128 + tid], s1);
    }
}

// Phase 2: 512 WGs x 256 grid-striding the worklist. 4 waves scan 8 chunks
// each (2-deep pipelining), LDS merge first-4-by-index with phase-1 partial,
// wave 0: gather+conv+hmax/hmin. Stats register-accumulated across entries;
// ONE atomic set per participating block at the end.
__global__ __launch_bounds__(256) void k_ball2(const float* __restrict__ x,
                                               const float* __restrict__ w,
                                               const float* __restrict__ bias,
                                               const float4* __restrict__ pk4,
                                               float* __restrict__ hx,
                                               float* __restrict__ hn,
                                               float* __restrict__ st,
                                               const int* __restrict__ wcnt,
                                               const int* __restrict__ wl,
                                               const int4* __restrict__ id4) {
    int tid = threadIdx.x;
    int wid = tid >> 6, lane = tid & 63;
    __shared__ int sCnt[4];
    __shared__ int sIds[4][4];

    float wc0[16], wc1[16];
    float bo0 = 0.0f, bo1 = 0.0f;
    if (wid == 0) {
        #pragma unroll
        for (int j = 0; j < 4; j++) {
            float4 a = *(const float4*)(w + lane * 16 + j * 4);
            float4 b2 = *(const float4*)(w + (lane + 64) * 16 + j * 4);
            wc0[j*4+0] = a.x;  wc0[j*4+1] = a.y;  wc0[j*4+2] = a.z;  wc0[j*4+3] = a.w;
            wc1[j*4+0] = b2.x; wc1[j*4+1] = b2.y; wc1[j*4+2] = b2.z; wc1[j*4+3] = b2.w;
        }
        bo0 = bias[lane]; bo1 = bias[lane + 64];
    }
    float asum0 = 0.0f, asq0 = 0.0f, asum1 = 0.0f, asq1 = 0.0f;

    int nstrag = *wcnt;
    for (int e = blockIdx.x; e < nstrag; e += gridDim.x) {
        int m = wl[e];
        int b = m >> 12, q = m & (N_ - 1);
        const float* xb = x + (size_t)b * (T_ * N_ * C_);
        const float* pts = xb + N_ * C_;
        const float4* pk = pk4 + b * 16384;
        float qx = xb[q * 16 + 0];
        float qy = xb[q * 16 + 1];
        float qz = xb[q * 16 + 2];
        float qn = (qx * qx + qy * qy) + qz * qz;

        int cstart = 1 + 8 * wid;
        int cend = cstart + 8; if (cend > 32) cend = 32;
        int y0 = 0, y1 = 0, y2 = 0, y3 = 0;     // named, no scratch
        int myc = 0;
        for (int c = cstart; c < cend && myc < 4; c += 2) {
            bool two = (c + 1 < cend);
            float4 pva[8], pvb[8];
            #pragma unroll
            for (int u = 0; u < 8; u++) pva[u] = pk[c * 512 + u * 64 + lane];
            if (two) {
                #pragma unroll
                for (int u = 0; u < 8; u++) pvb[u] = pk[(c + 1) * 512 + u * 64 + lane];
            }
            unsigned long long ma[8], mb[8];
            #pragma unroll
            for (int u = 0; u < 8; u++) {
                float dot = (qx * pva[u].x + qy * pva[u].y) + qz * pva[u].z;
                ma[u] = __ballot((qn + pva[u].w) - 2.0f * dot < 1.0f);
            }
            if (two) {
                #pragma unroll
                for (int u = 0; u < 8; u++) {
                    float dot = (qx * pvb[u].x + qy * pvb[u].y) + qz * pvb[u].z;
                    mb[u] = __ballot((qn + pvb[u].w) - 2.0f * dot < 1.0f);
                }
            }
            #pragma unroll
            for (int u = 0; u < 8; u++) {
                unsigned long long mask = ma[u];
                while (mask && myc < 4) {
                    int id = c * 512 + u * 64 + __builtin_ctzll(mask);
                    if (myc == 0)      y0 = id;
                    else if (myc == 1) y1 = id;
                    else if (myc == 2) y2 = id;
                    else               y3 = id;
                    myc++;
                    mask &= (mask - 1);
                }
            }
            if (two) {
                #pragma unroll
                for (int u = 0; u < 8; u++) {
                    unsigned long long mask = mb[u];
                    while (mask && myc < 4) {
                        int id = (c + 1) * 512 + u * 64 + __builtin_ctzll(mask);
                        if (myc == 0)      y0 = id;
                        else if (myc == 1) y1 = id;
                        else if (myc == 2) y2 = id;
                        else               y3 = id;
                        myc++;
                        mask &= (mask - 1);
                    }
                }
            }
        }
        if (lane == 0) {
            sCnt[wid] = myc;
            sIds[wid][0] = y0; sIds[wid][1] = y1;
            sIds[wid][2] = y2; sIds[wid][3] = y3;
        }
        __syncthreads();

        if (wid == 0) {                         // merge + epilogue on wave 0
            int4 p1 = id4[m];
            int f0 = 0, f1 = 0, f2 = 0, f3 = 0; // named, no scratch
            int fc = p1.w;
            if (fc > 0) f0 = p1.x;
            if (fc > 1) f1 = p1.y;
            if (fc > 2) f2 = p1.z;
            #pragma unroll
            for (int w2 = 0; w2 < 4; w2++) {
                int c2 = sCnt[w2];
                #pragma unroll
                for (int i = 0; i < 4; i++) {
                    if (i < c2 && fc < 4) {
                        int id = sIds[w2][i];
                        if (fc == 0)      f0 = id;
                        else if (fc == 1) f1 = id;
                        else if (fc == 2) f2 = id;
                        else              f3 = id;
                        fc++;
                    }
                }
            }
            if (fc >= 1) {
                if (fc <= 1) f1 = f0;
                if (fc <= 2) f2 = f0;
                if (fc <= 3) f3 = f0;
            }
            int fin[4] = {f0, f1, f2, f3};      // static-indexed below
            float a0[4], a1[4];
            if (fc == 0) {
                #pragma unroll
                for (int s = 0; s < 4; s++) { a0[s] = bo0; a1[s] = bo1; }
            } else {
                #pragma unroll
                for (int s = 0; s < 4; s++) {
                    const float* rp = pts + (size_t)fin[s] * 16;
                    float4 r0 = *(const float4*)(rp);
                    float4 r1 = *(const float4*)(rp + 4);
                    float4 r2 = *(const float4*)(rp + 8);
                    float4 r3 = *(const float4*)(rp + 12);
                    float s0 = bo0, s1 = bo1;
                    s0 += wc0[0] * r0.x;  s0 += wc0[1] * r0.y;  s0 += wc0[2] * r0.z;  s0 += wc0[3] * r0.w;
                    s0 += wc0[4] * r1.x;  s0 += wc0[5] * r1.y;  s0 += wc0[6] * r1.z;  s0 += wc0[7] * r1.w;
                    s0 += wc0[8] * r2.x;  s0 += wc0[9] * r2.y;  s0 += wc0[10] * r2.z; s0 += wc0[11] * r2.w;
                    s0 += wc0[12] * r3.x; s0 += wc0[13] * r3.y; s0 += wc0[14] * r3.z; s0 += wc0[15] * r3.w;
                    s1 += wc1[0] * r0.x;  s1 += wc1[1] * r0.y;  s1 += wc1[2] * r0.z;  s1 += wc1[3] * r0.w;
                    s1 += wc1[4] * r1.x;  s1 += wc1[5] * r1.y;  s1 += wc1[6] * r1.z;  s1 += wc1[7] * r1.w;
                    s1 += wc1[8] * r2.x;  s1 += wc1[9] * r2.y;  s1 += wc1[10] * r2.z; s1 += wc1[11] * r2.w;
                    s1 += wc1[12] * r3.x; s1 += wc1[13] * r3.y; s1 += wc1[14] * r3.z; s1 += wc1[15] * r3.w;
                    a0[s] = s0; a1[s] = s1;
                }
            }
            hx[(size_t)m * 128 + lane]      = fmaxf(fmaxf(a0[0], a0[1]), fmaxf(a0[2], a0[3]));
            hx[(size_t)m * 128 + 64 + lane] = fmaxf(fmaxf(a1[0], a1[1]), fmaxf(a1[2], a1[3]));
            hn[(size_t)m * 128 + lane]      = fminf(fminf(a0[0], a0[1]), fminf(a0[2], a0[3]));
            hn[(size_t)m * 128 + 64 + lane] = fminf(fminf(a1[0], a1[1]), fminf(a1[2], a1[3]));
            asum0 += (a0[0] + a0[1]) + (a0[2] + a0[3]);
            asq0  += (a0[0] * a0[0] + a0[1] * a0[1]) + (a0[2] * a0[2] + a0[3] * a0[3]);
            asum1 += (a1[0] + a1[1]) + (a1[2] + a1[3]);
            asq1  += (a1[0] * a1[0] + a1[1] * a1[1]) + (a1[2] * a1[2] + a1[3] * a1[3]);
        }
        __syncthreads();                        // LDS safe for next entry
    }
    if (wid == 0 && (int)blockIdx.x < nstrag) { // only blocks that did work
        float* stp = st + (blockIdx.x & (NPART - 1)) * 256;
        atomicAdd(&stp[lane], asum0);
        atomicAdd(&stp[64 + lane], asum1);
        atomicAdd(&stp[128 + lane], asq0);
        atomicAdd(&stp[192 + lane], asq1);
    }
}

// 512 WG x 256, m-tile 16. bn1 finalize from 32 partials; r = max(sc*hmax,
// sc*hmin)+sh; feature out; 3x 128x128 FC (packed weights + LDS broadcast);
// y write + branch stats into partial buffer blockIdx%32.
__global__ __launch_bounds__(256) void k_fc(const float* __restrict__ hx,
                                            const float* __restrict__ hn,
                                            float* __restrict__ st,
                                            const float4* __restrict__ wp,
                                            const float* __restrict__ b1,
                                            const float* __restrict__ b2,
                                            const float* __restrict__ b3,
                                            const float* __restrict__ bng,
                                            const float* __restrict__ bnb,
                                            float* __restrict__ y,
                                            float* __restrict__ out) {
    int tid = threadIdx.x;
    int m0 = blockIdx.x * 16;
    __shared__ float hs[2048];
    __shared__ float scsh[256];

    if (tid < 128) {                            // bn1 finalize from partials
        float s = 0.0f, q2 = 0.0f;
        #pragma unroll
        for (int p = 0; p < NPART; p++) {
            s  += st[p * 256 + tid];
            q2 += st[p * 256 + 128 + tid];
        }
        float mean = s * (1.0f / 32768.0f);
        float var = q2 * (1.0f / 32768.0f) - mean * mean;
        float sc = bng[tid] / sqrtf(fmaxf(var, 0.0f) + EPS_);
        scsh[tid] = sc;
        scsh[128 + tid] = bnb[tid] - mean * sc;
    }
    __syncthreads();

    for (int i = tid; i < 16 * 128; i += 256) {
        int ml = i >> 7, o = i & 127;
        float vx = hx[(size_t)(m0 + ml) * 128 + o];
        float vn = hn[(size_t)(m0 + ml) * 128 + o];
        float sc = scsh[o];
        float r = fmaxf(sc * vx, sc * vn) + scsh[128 + o];
        hs[ml * 128 + o] = r;
        out[(size_t)OUT_FEAT + (size_t)(m0 + ml) * 128 + o] = r;
    }
    __syncthreads();

    int o = tid & 127, gr = tid >> 7;
    int mbase = gr * 8;
    float acc[3][8];
    {
        float bb0 = b1[o], bb1 = b2[o], bb2 = b3[o];
        #pragma unroll
        for (int mm = 0; mm < 8; mm++) {
            acc[0][mm] = bb0; acc[1][mm] = bb1; acc[2][mm] = bb2;
        }
    }
    for (int c4 = 0; c4 < 32; c4++) {
        float4 w1v = wp[c4 * 128 + o];
        float4 w2v = wp[4096 + c4 * 128 + o];
        float4 w3v = wp[8192 + c4 * 128 + o];
        const float* hp = &hs[mbase * 128 + c4 * 4];
        #pragma unroll
        for (int mm = 0; mm < 8; mm++) {
            float4 hv = *(const float4*)(hp + mm * 128);
            acc[0][mm] += w1v.x * hv.x; acc[0][mm] += w1v.y * hv.y;
            acc[0][mm] += w1v.z * hv.z; acc[0][mm] += w1v.w * hv.w;
            acc[1][mm] += w2v.x * hv.x; acc[1][mm] += w2v.y * hv.y;
            acc[1][mm] += w2v.z * hv.z; acc[1][mm] += w2v.w * hv.w;
            acc[2][mm] += w3v.x * hv.x; acc[2][mm] += w3v.y * hv.y;
            acc[2][mm] += w3v.z * hv.z; acc[2][mm] += w3v.w * hv.w;
        }
    }
    __syncthreads();
    float psum[3], psq[3];
    #pragma unroll
    for (int k = 0; k < 3; k++) {
        float s = 0.0f, sq = 0.0f;
        float* yk = y + (size_t)k * M_ * 128;
        #pragma unroll
        for (int mm = 0; mm < 8; mm++) {
            float v = acc[k][mm];
            yk[(size_t)(m0 + mbase + mm) * 128 + o] = v;
            s += v; sq += v * v;
        }
        psum[k] = s; psq[k] = sq;
    }
    #pragma unroll
    for (int k = 0; k < 3; k++) {
        hs[(k * 2 + gr) * 128 + o] = psum[k];
        hs[768 + (k * 2 + gr) * 128 + o] = psq[k];
    }
    __syncthreads();
    float* bp = st + 8192 + (blockIdx.x & (NPART - 1)) * 768;
    for (int t = tid; t < 384; t += 256) {
        int k = t >> 7, oo = t & 127;
        float s  = hs[(k * 2) * 128 + oo] + hs[(k * 2 + 1) * 128 + oo];
        float sq = hs[768 + (k * 2) * 128 + oo] + hs[768 + (k * 2 + 1) * 128 + oo];
        atomicAdd(&bp[k * 256 + oo], s);
        atomicAdd(&bp[k * 256 + 128 + oo], sq);
    }
}

// 512 WG x 256 (4 waves, 4 rows/wave). Branch-BN finalize from 32 partials,
// bn+relu, head matmuls, 7 fp32 outputs per row.
__global__ __launch_bounds__(256) void k_heads(const float* __restrict__ y,
                                               const float* __restrict__ st,
                                               const float* __restrict__ wce, const float* __restrict__ bce,
                                               const float* __restrict__ wlwh, const float* __restrict__ blwh,
                                               const float* __restrict__ wth, const float* __restrict__ bth,
                                               const float* __restrict__ bng, const float* __restrict__ bnb,
                                               float* __restrict__ out) {
    int tid = threadIdx.x;
    __shared__ float bsc[768];
    for (int t = tid; t < 384; t += 256) {
        int k = t >> 7, o = t & 127;
        float s = 0.0f, q2 = 0.0f;
        #pragma unroll
        for (int p = 0; p < NPART; p++) {
            const float* bp = st + 8192 + p * 768 + k * 256;
            s  += bp[o];
            q2 += bp[128 + o];
        }
        float mean = s * (1.0f / 8192.0f);
        float var = q2 * (1.0f / 8192.0f) - mean * mean;
        float sc = bng[o] / sqrtf(fmaxf(var, 0.0f) + EPS_);
        bsc[k * 256 + o] = sc;
        bsc[k * 256 + 128 + o] = bnb[o] - mean * sc;
    }
    __syncthreads();

    int wave = tid >> 6, lane = tid & 63;
    const float* y1 = y;
    const float* y2 = y + (size_t)M_ * D_;
    const float* y3 = y + 2 * (size_t)M_ * D_;
    #pragma unroll
    for (int i = 0; i < 4; i++) {
        int m = blockIdx.x * 16 + wave * 4 + i;
        float p[7] = {0, 0, 0, 0, 0, 0, 0};
        #pragma unroll
        for (int cc = 0; cc < 2; cc++) {
            int c = lane + 64 * cc;
            float v1 = fmaxf(y1[(size_t)m * D_ + c] * bsc[c] + bsc[128 + c], 0.0f);
            float v2 = fmaxf(y2[(size_t)m * D_ + c] * bsc[256 + c] + bsc[384 + c], 0.0f);
            float v3 = fmaxf(y3[(size_t)m * D_ + c] * bsc[512 + c] + bsc[640 + c], 0.0f);
            p[0] += v1 * wce[c];
            p[1] += v1 * wce[128 + c];
            p[2] += v1 * wce[256 + c];
            p[3] += v2 * wlwh[c];
            p[4] += v2 * wlwh[128 + c];
            p[5] += v2 * wlwh[256 + c];
            p[6] += v3 * wth[c];
        }
        #pragma unroll
        for (int off = 32; off > 0; off >>= 1) {
            #pragma unroll
            for (int j = 0; j < 7; j++) p[j] += __shfl_xor(p[j], off);
        }
        if (lane == 0) {
            out[m * 7 + 0] = p[0] + bce[0];
            out[m * 7 + 1] = p[1] + bce[1];
            out[m * 7 + 2] = p[2] + bce[2];
            out[m * 7 + 3] = p[3] + blwh[0];
            out[m * 7 + 4] = p[4] + blwh[1];
            out[m * 7 + 5] = p[5] + blwh[2];
            out[m * 7 + 6] = p[6] + bth[0];
        }
    }
}

extern "C" void kernel_launch(void* const* d_in, const int* in_sizes, int n_in,
                              void* d_out, int out_size, void* d_ws, size_t ws_size,
                              hipStream_t stream) {
    (void)in_sizes; (void)n_in; (void)out_size; (void)ws_size;
    const float* x        = (const float*)d_in[0];
    const float* conv1_w  = (const float*)d_in[1];
    const float* conv1_b  = (const float*)d_in[2];
    const float* bn_g     = (const float*)d_in[3];
    const float* bn_b     = (const float*)d_in[4];
    const float* fc1_w    = (const float*)d_in[5];
    const float* fc1_b    = (const float*)d_in[6];
    const float* fc_ce_w  = (const float*)d_in[7];
    const float* fc_ce_b  = (const float*)d_in[8];
    const float* fc2_w    = (const float*)d_in[9];
    const float* fc2_b    = (const float*)d_in[10];
    const float* fc_lwh_w = (const float*)d_in[11];
    const float* fc_lwh_b = (const float*)d_in[12];
    const float* fc3_w    = (const float*)d_in[13];
    const float* fc3_b    = (const float*)d_in[14];
    const float* fc_th_w  = (const float*)d_in[15];
    const float* fc_th_b  = (const float*)d_in[16];

    float* ws = (float*)d_ws;
    float* hx = ws + HX_OFF;
    float* hn = ws + HN_OFF;
    float* y  = ws + Y_OFF;
    float* st = ws + ST_OFF;
    int*  wcnt = (int*)(ws + WL_OFF);
    int*  wl   = wcnt + 1;
    int4* id4  = (int4*)(ws + ID4_OFF);
    float4* wp  = (float4*)(ws + WP_OFF);
    float4* pk4 = (float4*)(ws + PK_OFF);
    float* out = (float*)d_out;

    // zero stats partials (32768 floats) + wcnt (adjacent) — memset node
    hipMemsetAsync(st, 0, (32768 + 1) * sizeof(float), stream);

    hipLaunchKernelGGL(k_ball1, dim3(1024), dim3(256), 0, stream,
                       x, conv1_w, conv1_b, fc1_w, fc2_w, fc3_w, wp, pk4,
                       hx, hn, st, wcnt, wl, id4);
    hipLaunchKernelGGL(k_ball2, dim3(512),  dim3(256), 0, stream,
                       x, conv1_w, conv1_b, pk4, hx, hn, st, wcnt, wl, id4);
    hipLaunchKernelGGL(k_fc,    dim3(512),  dim3(256), 0, stream, hx, hn, st, wp,
                       fc1_b, fc2_b, fc3_b, bn_g, bn_b, y, out);
    hipLaunchKernelGGL(k_heads, dim3(512),  dim3(256), 0, stream, y, st,
                       fc_ce_w, fc_ce_b, fc_lwh_w, fc_lwh_b, fc_th_w, fc_th_b, bn_g, bn_b, out);
}

// Round 4
// 145.928 us; speedup vs baseline: 2.7030x; 1.0430x over previous
//
#include <hip/hip_runtime.h>

#define B_   2
#define T_   5
#define N_   4096
#define C_   16
#define D_   128
#define S_   4
#define NS_  16384   // (T-1)*N
#define M_   8192    // B*N
#define EPS_ 1e-5f
#define NPART 32     // atomic partial buffers (contention killer)

// ---- ws layout (fp32 element offsets) ----
#define HX_OFF   0u         // hmax: M*128   (hmin dropped: bn_g==1 -> sc>0)
#define HN_OFF   1048576u   // (unused, kept for layout stability)
#define Y_OFF    2097152u   // y: 3*M*128
#define ST_OFF   5242880u   // stats partials: 32*256 (bn1) + 32*768 (branch) = 32768
#define WL_OFF   5275648u   // [0]=count (int), [1..8192]=straggler ids
#define ID4_OFF  5283848u   // int4 per query: (i0,i1,i2,cnt)
#define WP_OFF   5316616u   // packed transposed FC weights: 3*16384
#define PK_OFF   5365768u   // SoA scan data: 2*16384 float4
// bn1 partial p: st[p*256 + (0..127 sum | 128..255 sumsq)]
// branch partial p, branch k: st[8192 + p*768 + k*256 + (0..127 sum | 128..255 sq)]

#define OUT_FEAT 57344      // element offset of feature within d_out (fp32)

// 144 WGs x 256. WGs [0,128): pk4[b][j] = (px,py,pz,|p|^2).
// WGs [128,144): zero all 32768 stats floats + wcnt; pack FC weights transposed.
__global__ __launch_bounds__(256) void k_prep(const float* __restrict__ x,
                                              const float* __restrict__ fw1,
                                              const float* __restrict__ fw2,
                                              const float* __restrict__ fw3,
                                              float* __restrict__ st,
                                              int* __restrict__ wcnt,
                                              float4* __restrict__ wp,
                                              float4* __restrict__ pk4) {
    int tid = threadIdx.x;
    if (blockIdx.x < 128) {
        int row = blockIdx.x * 256 + tid;       // 0..32767
        int b = row >> 14, j = row & 16383;
        const float* p = x + (size_t)b * (T_ * N_ * C_) + N_ * C_ + (size_t)j * 16;
        float4 v = *(const float4*)p;
        float pn = (v.x * v.x + v.y * v.y) + v.z * v.z;   // same expr as scan
        pk4[row] = make_float4(v.x, v.y, v.z, pn);
        return;
    }
    int pb = blockIdx.x - 128;                  // 0..15
    int t0 = pb * 256 + tid;                    // 0..4095
    #pragma unroll
    for (int i = 0; i < 8; i++) st[t0 + 4096 * i] = 0.0f;   // 32768 floats
    if (pb == 0 && tid == 0) wcnt[0] = 0;
    int o = t0 >> 5, c4 = t0 & 31;              // 0..4095 float4s per FC
    const float* fws[3] = { fw1, fw2, fw3 };
    #pragma unroll
    for (int k = 0; k < 3; k++)
        wp[k * 4096 + c4 * 128 + o] = *(const float4*)(fws[k] + o * 128 + c4 * 4);
}

// Phase 1: 512 WGs x 256, 4 queries per wave, CHUNK 0 ONLY (512 pts, L2-hot).
// Chunk-0 point data loaded ONCE per wave (batch is wave-uniform across the
// 4 queries). Complete (cnt==4): gather+conv1 -> hmax only (bn_g==1 => BN
// scale > 0 => max-pool commutes with BN via hmax alone). Stats in registers;
// one LDS reduce + ONE atomic set per block into partial buffer blockIdx%32.
__global__ __launch_bounds__(256) void k_ball1(const float* __restrict__ x,
                                               const float* __restrict__ w,
                                               const float* __restrict__ bias,
                                               const float4* __restrict__ pk4,
                                               float* __restrict__ hx,
                                               float* __restrict__ st,
                                               int* __restrict__ wcnt,
                                               int* __restrict__ wl,
                                               int4* __restrict__ id4) {
    int tid = threadIdx.x;
    int wid = tid >> 6, lane = tid & 63;
    __shared__ float red[2][512];

    float wc0[16], wc1[16];                     // conv1 rows lane, lane+64
    #pragma unroll
    for (int j = 0; j < 4; j++) {
        float4 a = *(const float4*)(w + lane * 16 + j * 4);
        float4 b2 = *(const float4*)(w + (lane + 64) * 16 + j * 4);
        wc0[j*4+0] = a.x;  wc0[j*4+1] = a.y;  wc0[j*4+2] = a.z;  wc0[j*4+3] = a.w;
        wc1[j*4+0] = b2.x; wc1[j*4+1] = b2.y; wc1[j*4+2] = b2.z; wc1[j*4+3] = b2.w;
    }
    float bo0 = bias[lane], bo1 = bias[lane + 64];

    // chunk-0 candidates: hoisted, shared by all 4 queries of this wave
    int mbase = (blockIdx.x * 4 + wid) * 4;     // groups of 4 never straddle batch
    int b = mbase >> 12;
    const float* xb = x + (size_t)b * (T_ * N_ * C_);
    const float* pts = xb + N_ * C_;
    const float4* pk = pk4 + b * 16384;
    float4 pv[8];
    #pragma unroll
    for (int u = 0; u < 8; u++) pv[u] = pk[u * 64 + lane];

    float asum0 = 0.0f, asq0 = 0.0f, asum1 = 0.0f, asq1 = 0.0f;
    #pragma unroll
    for (int qi = 0; qi < 4; qi++) {
        int m = mbase + qi;
        int q = m & (N_ - 1);
        float qx = xb[q * 16 + 0];
        float qy = xb[q * 16 + 1];
        float qz = xb[q * 16 + 2];
        float qn = (qx * qx + qy * qy) + qz * qz;

        unsigned long long mk[8];
        #pragma unroll
        for (int u = 0; u < 8; u++) {
            float dot = (qx * pv[u].x + qy * pv[u].y) + qz * pv[u].z;
            mk[u] = __ballot((qn + pv[u].w) - 2.0f * dot < 1.0f);   // ref form
        }

        // extract first 4 set bits (ascending index), no scratch arrays
        int i0 = 0, i1 = 0, i2 = 0, i3 = 0, cnt = 0;
        unsigned long long m0 = mk[0];
        if (__builtin_popcountll(m0) >= 4) {    // fast path: ~95% of queries
            i0 = __builtin_ctzll(m0); m0 &= m0 - 1;
            i1 = __builtin_ctzll(m0); m0 &= m0 - 1;
            i2 = __builtin_ctzll(m0); m0 &= m0 - 1;
            i3 = __builtin_ctzll(m0);
            cnt = 4;
        } else {
            #pragma unroll
            for (int u = 0; u < 8; u++) {
                unsigned long long mask = mk[u];
                while (mask && cnt < 4) {       // wave-uniform
                    int id = u * 64 + __builtin_ctzll(mask);
                    if (cnt == 0)      i0 = id;
                    else if (cnt == 1) i1 = id;
                    else if (cnt == 2) i2 = id;
                    else               i3 = id;
                    cnt++;
                    mask &= (mask - 1);
                }
            }
        }

        if (cnt >= 4) {                         // complete: conv + hmax
            int ids[4] = {i0, i1, i2, i3};      // static-indexed below
            float a0[4], a1[4];
            #pragma unroll
            for (int s = 0; s < 4; s++) {
                const float* rp = pts + (size_t)ids[s] * 16;
                float4 r0 = *(const float4*)(rp);
                float4 r1 = *(const float4*)(rp + 4);
                float4 r2 = *(const float4*)(rp + 8);
                float4 r3 = *(const float4*)(rp + 12);
                float s0 = bo0, s1 = bo1;
                s0 += wc0[0] * r0.x;  s0 += wc0[1] * r0.y;  s0 += wc0[2] * r0.z;  s0 += wc0[3] * r0.w;
                s0 += wc0[4] * r1.x;  s0 += wc0[5] * r1.y;  s0 += wc0[6] * r1.z;  s0 += wc0[7] * r1.w;
                s0 += wc0[8] * r2.x;  s0 += wc0[9] * r2.y;  s0 += wc0[10] * r2.z; s0 += wc0[11] * r2.w;
                s0 += wc0[12] * r3.x; s0 += wc0[13] * r3.y; s0 += wc0[14] * r3.z; s0 += wc0[15] * r3.w;
                s1 += wc1[0] * r0.x;  s1 += wc1[1] * r0.y;  s1 += wc1[2] * r0.z;  s1 += wc1[3] * r0.w;
                s1 += wc1[4] * r1.x;  s1 += wc1[5] * r1.y;  s1 += wc1[6] * r1.z;  s1 += wc1[7] * r1.w;
                s1 += wc1[8] * r2.x;  s1 += wc1[9] * r2.y;  s1 += wc1[10] * r2.z; s1 += wc1[11] * r2.w;
                s1 += wc1[12] * r3.x; s1 += wc1[13] * r3.y; s1 += wc1[14] * r3.z; s1 += wc1[15] * r3.w;
                a0[s] = s0; a1[s] = s1;
            }
            hx[(size_t)m * 128 + lane]      = fmaxf(fmaxf(a0[0], a0[1]), fmaxf(a0[2], a0[3]));
            hx[(size_t)m * 128 + 64 + lane] = fmaxf(fmaxf(a1[0], a1[1]), fmaxf(a1[2], a1[3]));
            asum0 += (a0[0] + a0[1]) + (a0[2] + a0[3]);
            asq0  += (a0[0] * a0[0] + a0[1] * a0[1]) + (a0[2] * a0[2] + a0[3] * a0[3]);
            asum1 += (a1[0] + a1[1]) + (a1[2] + a1[3]);
            asq1  += (a1[0] * a1[0] + a1[1] * a1[1]) + (a1[2] * a1[2] + a1[3] * a1[3]);
        } else {                                // straggler: enqueue
            if (lane == 0) {
                int idx = atomicAdd(wcnt, 1);
                wl[idx] = m;
                id4[m] = make_int4(i0, i1, i2, cnt);
            }
        }
    }

    red[0][wid * 128 + lane]      = asum0;
    red[0][wid * 128 + 64 + lane] = asum1;
    red[1][wid * 128 + lane]      = asq0;
    red[1][wid * 128 + 64 + lane] = asq1;
    __syncthreads();
    if (tid < 128) {
        float* stp = st + (blockIdx.x & (NPART - 1)) * 256;
        float s0 = (red[0][tid] + red[0][128 + tid]) + (red[0][256 + tid] + red[0][384 + tid]);
        float s1 = (red[1][tid] + red[1][128 + tid]) + (red[1][256 + tid] + red[1][384 + tid]);
        atomicAdd(&stp[tid], s0);
        atomicAdd(&stp[128 + tid], s1);
    }
}

// Phase 2: 1024 WGs x 256 over the worklist (mostly <=1 entry per block).
// Surplus blocks exit BEFORE the weight preload. 4 waves scan 8 chunks each
// (2-deep pipelining), LDS merge first-4-by-index with phase-1 partial,
// wave 0: gather+conv+hmax. ONE atomic set per participating block.
__global__ __launch_bounds__(256) void k_ball2(const float* __restrict__ x,
                                               const float* __restrict__ w,
                                               const float* __restrict__ bias,
                                               const float4* __restrict__ pk4,
                                               float* __restrict__ hx,
                                               float* __restrict__ st,
                                               const int* __restrict__ wcnt,
                                               const int* __restrict__ wl,
                                               const int4* __restrict__ id4) {
    int tid = threadIdx.x;
    int nstrag = *wcnt;
    if ((int)blockIdx.x >= nstrag) return;      // before any preload work

    int wid = tid >> 6, lane = tid & 63;
    __shared__ int sCnt[4];
    __shared__ int sIds[4][4];

    float wc0[16], wc1[16];
    float bo0 = 0.0f, bo1 = 0.0f;
    if (wid == 0) {
        #pragma unroll
        for (int j = 0; j < 4; j++) {
            float4 a = *(const float4*)(w + lane * 16 + j * 4);
            float4 b2 = *(const float4*)(w + (lane + 64) * 16 + j * 4);
            wc0[j*4+0] = a.x;  wc0[j*4+1] = a.y;  wc0[j*4+2] = a.z;  wc0[j*4+3] = a.w;
            wc1[j*4+0] = b2.x; wc1[j*4+1] = b2.y; wc1[j*4+2] = b2.z; wc1[j*4+3] = b2.w;
        }
        bo0 = bias[lane]; bo1 = bias[lane + 64];
    }
    float asum0 = 0.0f, asq0 = 0.0f, asum1 = 0.0f, asq1 = 0.0f;

    for (int e = blockIdx.x; e < nstrag; e += gridDim.x) {
        int m = wl[e];
        int b = m >> 12, q = m & (N_ - 1);
        const float* xb = x + (size_t)b * (T_ * N_ * C_);
        const float* pts = xb + N_ * C_;
        const float4* pk = pk4 + b * 16384;
        float qx = xb[q * 16 + 0];
        float qy = xb[q * 16 + 1];
        float qz = xb[q * 16 + 2];
        float qn = (qx * qx + qy * qy) + qz * qz;

        int cstart = 1 + 8 * wid;
        int cend = cstart + 8; if (cend > 32) cend = 32;
        int y0 = 0, y1 = 0, y2 = 0, y3 = 0;     // named, no scratch
        int myc = 0;
        for (int c = cstart; c < cend && myc < 4; c += 2) {
            bool two = (c + 1 < cend);
            float4 pva[8], pvb[8];
            #pragma unroll
            for (int u = 0; u < 8; u++) pva[u] = pk[c * 512 + u * 64 + lane];
            if (two) {
                #pragma unroll
                for (int u = 0; u < 8; u++) pvb[u] = pk[(c + 1) * 512 + u * 64 + lane];
            }
            unsigned long long ma[8], mb[8];
            #pragma unroll
            for (int u = 0; u < 8; u++) {
                float dot = (qx * pva[u].x + qy * pva[u].y) + qz * pva[u].z;
                ma[u] = __ballot((qn + pva[u].w) - 2.0f * dot < 1.0f);
            }
            if (two) {
                #pragma unroll
                for (int u = 0; u < 8; u++) {
                    float dot = (qx * pvb[u].x + qy * pvb[u].y) + qz * pvb[u].z;
                    mb[u] = __ballot((qn + pvb[u].w) - 2.0f * dot < 1.0f);
                }
            }
            #pragma unroll
            for (int u = 0; u < 8; u++) {
                unsigned long long mask = ma[u];
                while (mask && myc < 4) {
                    int id = c * 512 + u * 64 + __builtin_ctzll(mask);
                    if (myc == 0)      y0 = id;
                    else if (myc == 1) y1 = id;
                    else if (myc == 2) y2 = id;
                    else               y3 = id;
                    myc++;
                    mask &= (mask - 1);
                }
            }
            if (two) {
                #pragma unroll
                for (int u = 0; u < 8; u++) {
                    unsigned long long mask = mb[u];
                    while (mask && myc < 4) {
                        int id = (c + 1) * 512 + u * 64 + __builtin_ctzll(mask);
                        if (myc == 0)      y0 = id;
                        else if (myc == 1) y1 = id;
                        else if (myc == 2) y2 = id;
                        else               y3 = id;
                        myc++;
                        mask &= (mask - 1);
                    }
                }
            }
        }
        if (lane == 0) {
            sCnt[wid] = myc;
            sIds[wid][0] = y0; sIds[wid][1] = y1;
            sIds[wid][2] = y2; sIds[wid][3] = y3;
        }
        __syncthreads();

        if (wid == 0) {                         // merge + epilogue on wave 0
            int4 p1 = id4[m];
            int f0 = 0, f1 = 0, f2 = 0, f3 = 0; // named, no scratch
            int fc = p1.w;
            if (fc > 0) f0 = p1.x;
            if (fc > 1) f1 = p1.y;
            if (fc > 2) f2 = p1.z;
            #pragma unroll
            for (int w2 = 0; w2 < 4; w2++) {
                int c2 = sCnt[w2];
                #pragma unroll
                for (int i = 0; i < 4; i++) {
                    if (i < c2 && fc < 4) {
                        int id = sIds[w2][i];
                        if (fc == 0)      f0 = id;
                        else if (fc == 1) f1 = id;
                        else if (fc == 2) f2 = id;
                        else              f3 = id;
                        fc++;
                    }
                }
            }
            if (fc >= 1) {
                if (fc <= 1) f1 = f0;
                if (fc <= 2) f2 = f0;
                if (fc <= 3) f3 = f0;
            }
            int fin[4] = {f0, f1, f2, f3};      // static-indexed below
            float a0[4], a1[4];
            if (fc == 0) {
                #pragma unroll
                for (int s = 0; s < 4; s++) { a0[s] = bo0; a1[s] = bo1; }
            } else {
                #pragma unroll
                for (int s = 0; s < 4; s++) {
                    const float* rp = pts + (size_t)fin[s] * 16;
                    float4 r0 = *(const float4*)(rp);
                    float4 r1 = *(const float4*)(rp + 4);
                    float4 r2 = *(const float4*)(rp + 8);
                    float4 r3 = *(const float4*)(rp + 12);
                    float s0 = bo0, s1 = bo1;
                    s0 += wc0[0] * r0.x;  s0 += wc0[1] * r0.y;  s0 += wc0[2] * r0.z;  s0 += wc0[3] * r0.w;
                    s0 += wc0[4] * r1.x;  s0 += wc0[5] * r1.y;  s0 += wc0[6] * r1.z;  s0 += wc0[7] * r1.w;
                    s0 += wc0[8] * r2.x;  s0 += wc0[9] * r2.y;  s0 += wc0[10] * r2.z; s0 += wc0[11] * r2.w;
                    s0 += wc0[12] * r3.x; s0 += wc0[13] * r3.y; s0 += wc0[14] * r3.z; s0 += wc0[15] * r3.w;
                    s1 += wc1[0] * r0.x;  s1 += wc1[1] * r0.y;  s1 += wc1[2] * r0.z;  s1 += wc1[3] * r0.w;
                    s1 += wc1[4] * r1.x;  s1 += wc1[5] * r1.y;  s1 += wc1[6] * r1.z;  s1 += wc1[7] * r1.w;
                    s1 += wc1[8] * r2.x;  s1 += wc1[9] * r2.y;  s1 += wc1[10] * r2.z; s1 += wc1[11] * r2.w;
                    s1 += wc1[12] * r3.x; s1 += wc1[13] * r3.y; s1 += wc1[14] * r3.z; s1 += wc1[15] * r3.w;
                    a0[s] = s0; a1[s] = s1;
                }
            }
            hx[(size_t)m * 128 + lane]      = fmaxf(fmaxf(a0[0], a0[1]), fmaxf(a0[2], a0[3]));
            hx[(size_t)m * 128 + 64 + lane] = fmaxf(fmaxf(a1[0], a1[1]), fmaxf(a1[2], a1[3]));
            asum0 += (a0[0] + a0[1]) + (a0[2] + a0[3]);
            asq0  += (a0[0] * a0[0] + a0[1] * a0[1]) + (a0[2] * a0[2] + a0[3] * a0[3]);
            asum1 += (a1[0] + a1[1]) + (a1[2] + a1[3]);
            asq1  += (a1[0] * a1[0] + a1[1] * a1[1]) + (a1[2] * a1[2] + a1[3] * a1[3]);
        }
        __syncthreads();                        // LDS safe for next entry
    }
    if (wid == 0) {                             // one atomic set per block
        float* stp = st + (blockIdx.x & (NPART - 1)) * 256;
        atomicAdd(&stp[lane], asum0);
        atomicAdd(&stp[64 + lane], asum1);
        atomicAdd(&stp[128 + lane], asq0);
        atomicAdd(&stp[192 + lane], asq1);
    }
}

// 512 WG x 256, m-tile 16. bn1 finalize from 32 partials; r = sc*hmax + sh
// (sc>0 guaranteed: bn_g==1); feature out; 3x 128x128 FC (packed weights +
// LDS broadcast); y write + branch stats into partial buffer blockIdx%32.
__global__ __launch_bounds__(256) void k_fc(const float* __restrict__ hx,
                                            float* __restrict__ st,
                                            const float4* __restrict__ wp,
                                            const float* __restrict__ b1,
                                            const float* __restrict__ b2,
                                            const float* __restrict__ b3,
                                            const float* __restrict__ bng,
                                            const float* __restrict__ bnb,
                                            float* __restrict__ y,
                                            float* __restrict__ out) {
    int tid = threadIdx.x;
    int m0 = blockIdx.x * 16;
    __shared__ float hs[2048];
    __shared__ float scsh[256];

    if (tid < 128) {                            // bn1 finalize from partials
        float s = 0.0f, q2 = 0.0f;
        #pragma unroll
        for (int p = 0; p < NPART; p++) {
            s  += st[p * 256 + tid];
            q2 += st[p * 256 + 128 + tid];
        }
        float mean = s * (1.0f / 32768.0f);
        float var = q2 * (1.0f / 32768.0f) - mean * mean;
        float sc = bng[tid] / sqrtf(fmaxf(var, 0.0f) + EPS_);
        scsh[tid] = sc;
        scsh[128 + tid] = bnb[tid] - mean * sc;
    }
    __syncthreads();

    for (int i = tid; i < 16 * 128; i += 256) {
        int ml = i >> 7, o = i & 127;
        float vx = hx[(size_t)(m0 + ml) * 128 + o];
        float r = scsh[o] * vx + scsh[128 + o];
        hs[ml * 128 + o] = r;
        out[(size_t)OUT_FEAT + (size_t)(m0 + ml) * 128 + o] = r;
    }
    __syncthreads();

    int o = tid & 127, gr = tid >> 7;
    int mbase = gr * 8;
    float acc[3][8];
    {
        float bb0 = b1[o], bb1 = b2[o], bb2 = b3[o];
        #pragma unroll
        for (int mm = 0; mm < 8; mm++) {
            acc[0][mm] = bb0; acc[1][mm] = bb1; acc[2][mm] = bb2;
        }
    }
    for (int c4 = 0; c4 < 32; c4++) {
        float4 w1v = wp[c4 * 128 + o];
        float4 w2v = wp[4096 + c4 * 128 + o];
        float4 w3v = wp[8192 + c4 * 128 + o];
        const float* hp = &hs[mbase * 128 + c4 * 4];
        #pragma unroll
        for (int mm = 0; mm < 8; mm++) {
            float4 hv = *(const float4*)(hp + mm * 128);
            acc[0][mm] += w1v.x * hv.x; acc[0][mm] += w1v.y * hv.y;
            acc[0][mm] += w1v.z * hv.z; acc[0][mm] += w1v.w * hv.w;
            acc[1][mm] += w2v.x * hv.x; acc[1][mm] += w2v.y * hv.y;
            acc[1][mm] += w2v.z * hv.z; acc[1][mm] += w2v.w * hv.w;
            acc[2][mm] += w3v.x * hv.x; acc[2][mm] += w3v.y * hv.y;
            acc[2][mm] += w3v.z * hv.z; acc[2][mm] += w3v.w * hv.w;
        }
    }
    __syncthreads();
    float psum[3], psq[3];
    #pragma unroll
    for (int k = 0; k < 3; k++) {
        float s = 0.0f, sq = 0.0f;
        float* yk = y + (size_t)k * M_ * 128;
        #pragma unroll
        for (int mm = 0; mm < 8; mm++) {
            float v = acc[k][mm];
            yk[(size_t)(m0 + mbase + mm) * 128 + o] = v;
            s += v; sq += v * v;
        }
        psum[k] = s; psq[k] = sq;
    }
    #pragma unroll
    for (int k = 0; k < 3; k++) {
        hs[(k * 2 + gr) * 128 + o] = psum[k];
        hs[768 + (k * 2 + gr) * 128 + o] = psq[k];
    }
    __syncthreads();
    float* bp = st + 8192 + (blockIdx.x & (NPART - 1)) * 768;
    for (int t = tid; t < 384; t += 256) {
        int k = t >> 7, oo = t & 127;
        float s  = hs[(k * 2) * 128 + oo] + hs[(k * 2 + 1) * 128 + oo];
        float sq = hs[768 + (k * 2) * 128 + oo] + hs[768 + (k * 2 + 1) * 128 + oo];
        atomicAdd(&bp[k * 256 + oo], s);
        atomicAdd(&bp[k * 256 + 128 + oo], sq);
    }
}

// 256 WG x 256 (4 waves, 8 rows/wave). Branch-BN finalize from 32 partials
// (redundancy halved vs 512 blocks), bn+relu, head matmuls, 7 fp32/row.
__global__ __launch_bounds__(256) void k_heads(const float* __restrict__ y,
                                               const float* __restrict__ st,
                                               const float* __restrict__ wce, const float* __restrict__ bce,
                                               const float* __restrict__ wlwh, const float* __restrict__ blwh,
                                               const float* __restrict__ wth, const float* __restrict__ bth,
                                               const float* __restrict__ bng, const float* __restrict__ bnb,
                                               float* __restrict__ out) {
    int tid = threadIdx.x;
    __shared__ float bsc[768];
    for (int t = tid; t < 384; t += 256) {
        int k = t >> 7, o = t & 127;
        float s = 0.0f, q2 = 0.0f;
        #pragma unroll
        for (int p = 0; p < NPART; p++) {
            const float* bp = st + 8192 + p * 768 + k * 256;
            s  += bp[o];
            q2 += bp[128 + o];
        }
        float mean = s * (1.0f / 8192.0f);
        float var = q2 * (1.0f / 8192.0f) - mean * mean;
        float sc = bng[o] / sqrtf(fmaxf(var, 0.0f) + EPS_);
        bsc[k * 256 + o] = sc;
        bsc[k * 256 + 128 + o] = bnb[o] - mean * sc;
    }
    __syncthreads();

    int wave = tid >> 6, lane = tid & 63;
    const float* y1 = y;
    const float* y2 = y + (size_t)M_ * D_;
    const float* y3 = y + 2 * (size_t)M_ * D_;
    #pragma unroll
    for (int i = 0; i < 8; i++) {
        int m = blockIdx.x * 32 + wave * 8 + i;
        float p[7] = {0, 0, 0, 0, 0, 0, 0};
        #pragma unroll
        for (int cc = 0; cc < 2; cc++) {
            int c = lane + 64 * cc;
            float v1 = fmaxf(y1[(size_t)m * D_ + c] * bsc[c] + bsc[128 + c], 0.0f);
            float v2 = fmaxf(y2[(size_t)m * D_ + c] * bsc[256 + c] + bsc[384 + c], 0.0f);
            float v3 = fmaxf(y3[(size_t)m * D_ + c] * bsc[512 + c] + bsc[640 + c], 0.0f);
            p[0] += v1 * wce[c];
            p[1] += v1 * wce[128 + c];
            p[2] += v1 * wce[256 + c];
            p[3] += v2 * wlwh[c];
            p[4] += v2 * wlwh[128 + c];
            p[5] += v2 * wlwh[256 + c];
            p[6] += v3 * wth[c];
        }
        #pragma unroll
        for (int off = 32; off > 0; off >>= 1) {
            #pragma unroll
            for (int j = 0; j < 7; j++) p[j] += __shfl_xor(p[j], off);
        }
        if (lane == 0) {
            out[m * 7 + 0] = p[0] + bce[0];
            out[m * 7 + 1] = p[1] + bce[1];
            out[m * 7 + 2] = p[2] + bce[2];
            out[m * 7 + 3] = p[3] + blwh[0];
            out[m * 7 + 4] = p[4] + blwh[1];
            out[m * 7 + 5] = p[5] + blwh[2];
            out[m * 7 + 6] = p[6] + bth[0];
        }
    }
}

extern "C" void kernel_launch(void* const* d_in, const int* in_sizes, int n_in,
                              void* d_out, int out_size, void* d_ws, size_t ws_size,
                              hipStream_t stream) {
    (void)in_sizes; (void)n_in; (void)out_size; (void)ws_size;
    const float* x        = (const float*)d_in[0];
    const float* conv1_w  = (const float*)d_in[1];
    const float* conv1_b  = (const float*)d_in[2];
    const float* bn_g     = (const float*)d_in[3];
    const float* bn_b     = (const float*)d_in[4];
    const float* fc1_w    = (const float*)d_in[5];
    const float* fc1_b    = (const float*)d_in[6];
    const float* fc_ce_w  = (const float*)d_in[7];
    const float* fc_ce_b  = (const float*)d_in[8];
    const float* fc2_w    = (const float*)d_in[9];
    const float* fc2_b    = (const float*)d_in[10];
    const float* fc_lwh_w = (const float*)d_in[11];
    const float* fc_lwh_b = (const float*)d_in[12];
    const float* fc3_w    = (const float*)d_in[13];
    const float* fc3_b    = (const float*)d_in[14];
    const float* fc_th_w  = (const float*)d_in[15];
    const float* fc_th_b  = (const float*)d_in[16];

    float* ws = (float*)d_ws;
    float* hx = ws + HX_OFF;
    float* y  = ws + Y_OFF;
    float* st = ws + ST_OFF;
    int*  wcnt = (int*)(ws + WL_OFF);
    int*  wl   = wcnt + 1;
    int4* id4  = (int4*)(ws + ID4_OFF);
    float4* wp  = (float4*)(ws + WP_OFF);
    float4* pk4 = (float4*)(ws + PK_OFF);
    float* out = (float*)d_out;

    hipLaunchKernelGGL(k_prep,  dim3(144),  dim3(256), 0, stream,
                       x, fc1_w, fc2_w, fc3_w, st, wcnt, wp, pk4);
    hipLaunchKernelGGL(k_ball1, dim3(512),  dim3(256), 0, stream,
                       x, conv1_w, conv1_b, pk4, hx, st, wcnt, wl, id4);
    hipLaunchKernelGGL(k_ball2, dim3(1024), dim3(256), 0, stream,
                       x, conv1_w, conv1_b, pk4, hx, st, wcnt, wl, id4);
    hipLaunchKernelGGL(k_fc,    dim3(512),  dim3(256), 0, stream, hx, st, wp,
                       fc1_b, fc2_b, fc3_b, bn_g, bn_b, y, out);
    hipLaunchKernelGGL(k_heads, dim3(256),  dim3(256), 0, stream, y, st,
                       fc_ce_w, fc_ce_b, fc_lwh_w, fc_lwh_b, fc_th_w, fc_th_b, bn_g, bn_b, out);
}